// Round 1
// baseline (572.457 us; speedup 1.0000x reference)
//
#include <hip/hip_runtime.h>

#define N_NODES 50000
#define N_EDGES 600000
#define D 128
#define NLAYERS 3

// ---------------- CSR build ----------------

__global__ void hist_kernel(const int* __restrict__ dst, int* __restrict__ deg) {
    int e = blockIdx.x * blockDim.x + threadIdx.x;
    if (e < N_EDGES) atomicAdd(&deg[dst[e]], 1);
}

__global__ void scan_kernel(const int* __restrict__ deg, int* __restrict__ row_start,
                            float* __restrict__ inv_deg) {
    __shared__ int psum[1024];
    int tid = threadIdx.x;
    const int chunk = (N_NODES + 1023) / 1024;
    int s = tid * chunk;
    int e = min(s + chunk, N_NODES);
    int sum = 0;
    for (int i = s; i < e; i++) sum += deg[i];
    psum[tid] = sum;
    __syncthreads();
    if (tid == 0) {
        int run = 0;
        for (int i = 0; i < 1024; i++) { int t = psum[i]; psum[i] = run; run += t; }
        row_start[N_NODES] = run;
    }
    __syncthreads();
    int run = psum[tid];
    for (int i = s; i < e; i++) {
        row_start[i] = run;
        int d = deg[i];
        inv_deg[i] = 1.0f / fmaxf((float)d, 1.0f);
        run += d;
    }
}

__global__ void fill_kernel(const int* __restrict__ src, const int* __restrict__ dst,
                            const int* __restrict__ row_start, int* __restrict__ cursor,
                            int* __restrict__ csr_src) {
    int e = blockIdx.x * blockDim.x + threadIdx.x;
    if (e < N_EDGES) {
        int d_ = dst[e];
        int pos = atomicAdd(&cursor[d_], 1);
        csr_src[row_start[d_] + pos] = src[e];
    }
}

// ---------------- mean aggregation (gather over CSR) ----------------
// 8 nodes per 256-thread block; 32 lanes per node, float4 per lane.

__global__ void agg_kernel(const float* __restrict__ h, const int* __restrict__ row_start,
                           const int* __restrict__ csr_src, const float* __restrict__ inv_deg,
                           float* __restrict__ agg) {
    int node = blockIdx.x * 8 + (threadIdx.x >> 5);
    int q = threadIdx.x & 31;
    if (node >= N_NODES) return;
    int beg = row_start[node], end = row_start[node + 1];
    float4 acc = make_float4(0.f, 0.f, 0.f, 0.f);
    for (int e = beg; e < end; e++) {
        int s = csr_src[e];
        float4 v = ((const float4*)(h + (size_t)s * D))[q];
        acc.x += v.x; acc.y += v.y; acc.z += v.z; acc.w += v.w;
    }
    float w = inv_deg[node];
    acc.x *= w; acc.y *= w; acc.z *= w; acc.w *= w;
    ((float4*)(agg + (size_t)node * D))[q] = acc;
}

// ---------------- fused dual GEMM: hout = relu(agg@Wl + bl + hin@Wr) ----------------
// Block: 64 rows x 128 cols, BK=32, 256 threads, 8x4 register tile per thread.

#define BM 64
#define BK 32
#define APAD 68   // padded row stride for transposed activation tiles (16B-aligned, conflict-light)

__global__ __launch_bounds__(256) void gemm_kernel(
    const float* __restrict__ agg, const float* __restrict__ hin,
    const float* __restrict__ Wl, const float* __restrict__ Wr,
    const float* __restrict__ bl, float* __restrict__ hout) {
    __shared__ float wl_s[BK][D];
    __shared__ float wr_s[BK][D];
    __shared__ float a_s[BK][APAD];
    __shared__ float h_s[BK][APAD];

    int tid = threadIdx.x;
    int tx = tid & 31;   // col group: cols tx*4 .. tx*4+3
    int ty = tid >> 5;   // row group: rows ty*8 .. ty*8+7
    int row0 = blockIdx.x * BM;

    float acc[8][4];
    float4 bv = *((const float4*)(bl + tx * 4));
    #pragma unroll
    for (int r = 0; r < 8; r++) {
        acc[r][0] = bv.x; acc[r][1] = bv.y; acc[r][2] = bv.z; acc[r][3] = bv.w;
    }

    for (int kt = 0; kt < D; kt += BK) {
        // stage W tiles: 32x128 each
        #pragma unroll
        for (int i = 0; i < 4; i++) {
            int f4 = tid + i * 256;          // 0..1023
            int kk = f4 >> 5;                // row in [0,32)
            int cc = (f4 & 31) * 4;          // col
            *((float4*)&wl_s[kk][cc]) = *((const float4*)(Wl + (size_t)(kt + kk) * D + cc));
            *((float4*)&wr_s[kk][cc]) = *((const float4*)(Wr + (size_t)(kt + kk) * D + cc));
        }
        // stage activation tiles transposed: [k][row]
        #pragma unroll
        for (int i = 0; i < 2; i++) {
            int f4 = tid + i * 256;          // 0..511
            int rr = f4 >> 3;                // row in [0,64)
            int kk = (f4 & 7) * 4;           // k offset
            int grow = min(row0 + rr, N_NODES - 1);   // clamp for tail block (read-only)
            float4 av = *((const float4*)(agg + (size_t)grow * D + kt + kk));
            a_s[kk + 0][rr] = av.x; a_s[kk + 1][rr] = av.y;
            a_s[kk + 2][rr] = av.z; a_s[kk + 3][rr] = av.w;
            float4 hv = *((const float4*)(hin + (size_t)grow * D + kt + kk));
            h_s[kk + 0][rr] = hv.x; h_s[kk + 1][rr] = hv.y;
            h_s[kk + 2][rr] = hv.z; h_s[kk + 3][rr] = hv.w;
        }
        __syncthreads();
        #pragma unroll
        for (int k = 0; k < BK; k++) {
            float4 wl4 = *((const float4*)&wl_s[k][tx * 4]);
            float4 wr4 = *((const float4*)&wr_s[k][tx * 4]);
            float4 a0 = *((const float4*)&a_s[k][ty * 8]);
            float4 a1 = *((const float4*)&a_s[k][ty * 8 + 4]);
            float4 h0 = *((const float4*)&h_s[k][ty * 8]);
            float4 h1 = *((const float4*)&h_s[k][ty * 8 + 4]);
            float ar[8] = {a0.x, a0.y, a0.z, a0.w, a1.x, a1.y, a1.z, a1.w};
            float hr[8] = {h0.x, h0.y, h0.z, h0.w, h1.x, h1.y, h1.z, h1.w};
            #pragma unroll
            for (int r = 0; r < 8; r++) {
                acc[r][0] += ar[r] * wl4.x; acc[r][0] += hr[r] * wr4.x;
                acc[r][1] += ar[r] * wl4.y; acc[r][1] += hr[r] * wr4.y;
                acc[r][2] += ar[r] * wl4.z; acc[r][2] += hr[r] * wr4.z;
                acc[r][3] += ar[r] * wl4.w; acc[r][3] += hr[r] * wr4.w;
            }
        }
        __syncthreads();
    }
    #pragma unroll
    for (int r = 0; r < 8; r++) {
        int row = row0 + ty * 8 + r;
        if (row < N_NODES) {
            float4 o;
            o.x = fmaxf(acc[r][0], 0.f);
            o.y = fmaxf(acc[r][1], 0.f);
            o.z = fmaxf(acc[r][2], 0.f);
            o.w = fmaxf(acc[r][3], 0.f);
            *((float4*)(hout + (size_t)row * D + tx * 4)) = o;
        }
    }
}

// ---------------- readout: out[i] = h[i] . W_out + b_out ----------------

__global__ void out_kernel(const float* __restrict__ h, const float* __restrict__ Wout,
                           const float* __restrict__ bout, float* __restrict__ out) {
    int node = blockIdx.x * 4 + (threadIdx.x >> 6);
    int lane = threadIdx.x & 63;
    if (node >= N_NODES) return;
    const float* hr = h + (size_t)node * D;
    float v = hr[lane] * Wout[lane] + hr[lane + 64] * Wout[lane + 64];
    #pragma unroll
    for (int off = 32; off > 0; off >>= 1) v += __shfl_down(v, off, 64);
    if (lane == 0) out[node] = v + bout[0];
}

// ---------------- launch ----------------

extern "C" void kernel_launch(void* const* d_in, const int* in_sizes, int n_in,
                              void* d_out, int out_size, void* d_ws, size_t ws_size,
                              hipStream_t stream) {
    const float* x     = (const float*)d_in[0];
    const int*   edge  = (const int*)d_in[1];   // [2, E] flattened: src then dst
    const float* W_l   = (const float*)d_in[2]; // [3,128,128]
    const float* b_l   = (const float*)d_in[3]; // [3,128]
    const float* W_r   = (const float*)d_in[4]; // [3,128,128]
    const float* W_out = (const float*)d_in[5]; // [128]
    const float* b_out = (const float*)d_in[6]; // [1]
    float* out = (float*)d_out;

    char* ws = (char*)d_ws;
    size_t off = 0;
    auto alloc = [&](size_t bytes) -> void* {
        void* p = ws + off;
        off += (bytes + 255) & ~(size_t)255;
        return p;
    };
    float* h        = (float*)alloc((size_t)N_NODES * D * sizeof(float));
    float* agg      = (float*)alloc((size_t)N_NODES * D * sizeof(float));
    int*   deg      = (int*)alloc((size_t)N_NODES * sizeof(int));
    int*   row_start= (int*)alloc((size_t)(N_NODES + 1) * sizeof(int));
    int*   cursor   = (int*)alloc((size_t)N_NODES * sizeof(int));
    float* inv_deg  = (float*)alloc((size_t)N_NODES * sizeof(float));
    int*   csr_src  = (int*)alloc((size_t)N_EDGES * sizeof(int));

    const int* src = edge;
    const int* dst = edge + N_EDGES;

    hipMemsetAsync(deg, 0, (size_t)N_NODES * sizeof(int), stream);
    hipMemsetAsync(cursor, 0, (size_t)N_NODES * sizeof(int), stream);

    hist_kernel<<<(N_EDGES + 255) / 256, 256, 0, stream>>>(dst, deg);
    scan_kernel<<<1, 1024, 0, stream>>>(deg, row_start, inv_deg);
    fill_kernel<<<(N_EDGES + 255) / 256, 256, 0, stream>>>(src, dst, row_start, cursor, csr_src);

    const int agg_grid = (N_NODES + 7) / 8;
    const int gemm_grid = (N_NODES + BM - 1) / BM;

    // layer 0: h_in = x
    agg_kernel<<<agg_grid, 256, 0, stream>>>(x, row_start, csr_src, inv_deg, agg);
    gemm_kernel<<<gemm_grid, 256, 0, stream>>>(agg, x, W_l, W_r, b_l, h);
    // layers 1..2: in-place on h
    for (int l = 1; l < NLAYERS; l++) {
        agg_kernel<<<agg_grid, 256, 0, stream>>>(h, row_start, csr_src, inv_deg, agg);
        gemm_kernel<<<gemm_grid, 256, 0, stream>>>(agg, h,
            W_l + (size_t)l * D * D, W_r + (size_t)l * D * D, b_l + (size_t)l * D, h);
    }
    out_kernel<<<(N_NODES + 3) / 4, 256, 0, stream>>>(h, W_out, b_out, out);
}

// Round 2
// 465.363 us; speedup vs baseline: 1.2301x; 1.2301x over previous
//
#include <hip/hip_runtime.h>

#define N_NODES 50000
#define N_EDGES 600000
#define D 128
#define NLAYERS 3

#define SCAN_BLOCK 256
#define N_SCAN_BLOCKS ((N_NODES + SCAN_BLOCK - 1) / SCAN_BLOCK)   // 196

// ---------------- CSR build ----------------

__global__ void hist_kernel(const int* __restrict__ dst, int* __restrict__ deg) {
    int e = blockIdx.x * blockDim.x + threadIdx.x;
    if (e < N_EDGES) atomicAdd(&deg[dst[e]], 1);
}

// Phase A: per-block sums of deg
__global__ void block_sum_kernel(const int* __restrict__ deg, int* __restrict__ block_sums) {
    int tid = threadIdx.x;
    int i = blockIdx.x * SCAN_BLOCK + tid;
    int v = (i < N_NODES) ? deg[i] : 0;
    #pragma unroll
    for (int off = 32; off > 0; off >>= 1) v += __shfl_down(v, off, 64);
    __shared__ int wsum[4];
    if ((tid & 63) == 0) wsum[tid >> 6] = v;
    __syncthreads();
    if (tid == 0) block_sums[blockIdx.x] = wsum[0] + wsum[1] + wsum[2] + wsum[3];
}

// Phase B: exclusive-scan the 196 block sums in a single block
__global__ void scan_sums_kernel(int* __restrict__ block_sums, int* __restrict__ row_start) {
    __shared__ int s[SCAN_BLOCK];
    int tid = threadIdx.x;
    int v = (tid < N_SCAN_BLOCKS) ? block_sums[tid] : 0;
    s[tid] = v;
    __syncthreads();
    #pragma unroll
    for (int off = 1; off < SCAN_BLOCK; off <<= 1) {
        int t = (tid >= off) ? s[tid - off] : 0;
        __syncthreads();
        s[tid] += t;
        __syncthreads();
    }
    if (tid < N_SCAN_BLOCKS) block_sums[tid] = s[tid] - v;   // exclusive
    if (tid == SCAN_BLOCK - 1) row_start[N_NODES] = s[SCAN_BLOCK - 1];
}

// Phase C: block-local exclusive scan + block offset -> row_start, inv_deg
__global__ void scan_final_kernel(const int* __restrict__ deg, const int* __restrict__ block_sums,
                                  int* __restrict__ row_start, float* __restrict__ inv_deg) {
    __shared__ int s[SCAN_BLOCK];
    int tid = threadIdx.x;
    int i = blockIdx.x * SCAN_BLOCK + tid;
    int v = (i < N_NODES) ? deg[i] : 0;
    s[tid] = v;
    __syncthreads();
    #pragma unroll
    for (int off = 1; off < SCAN_BLOCK; off <<= 1) {
        int t = (tid >= off) ? s[tid - off] : 0;
        __syncthreads();
        s[tid] += t;
        __syncthreads();
    }
    if (i < N_NODES) {
        row_start[i] = s[tid] - v + block_sums[blockIdx.x];
        inv_deg[i] = 1.0f / fmaxf((float)v, 1.0f);
    }
}

__global__ void fill_kernel(const int* __restrict__ src, const int* __restrict__ dst,
                            const int* __restrict__ row_start, int* __restrict__ cursor,
                            int* __restrict__ csr_src) {
    int e = blockIdx.x * blockDim.x + threadIdx.x;
    if (e < N_EDGES) {
        int d_ = dst[e];
        int pos = atomicAdd(&cursor[d_], 1);
        csr_src[row_start[d_] + pos] = src[e];
    }
}

// ---------------- mean aggregation (gather over CSR) ----------------
// 8 nodes per 256-thread block; 32 lanes per node, float4 per lane.

__global__ void agg_kernel(const float* __restrict__ h, const int* __restrict__ row_start,
                           const int* __restrict__ csr_src, const float* __restrict__ inv_deg,
                           float* __restrict__ agg) {
    int node = blockIdx.x * 8 + (threadIdx.x >> 5);
    int q = threadIdx.x & 31;
    if (node >= N_NODES) return;
    int beg = row_start[node], end = row_start[node + 1];
    float4 acc = make_float4(0.f, 0.f, 0.f, 0.f);
    for (int e = beg; e < end; e++) {
        int s = csr_src[e];
        float4 v = ((const float4*)(h + (size_t)s * D))[q];
        acc.x += v.x; acc.y += v.y; acc.z += v.z; acc.w += v.w;
    }
    float w = inv_deg[node];
    acc.x *= w; acc.y *= w; acc.z *= w; acc.w *= w;
    ((float4*)(agg + (size_t)node * D))[q] = acc;
}

// ---------------- fused dual GEMM: hout = relu(agg@Wl + bl + hin@Wr) ----------------
// Block: 64 rows x 128 cols, BK=32, 256 threads, 8x4 register tile per thread.

#define BM 64
#define BK 32
#define APAD 68   // padded row stride for transposed activation tiles

__global__ __launch_bounds__(256) void gemm_kernel(
    const float* __restrict__ agg, const float* __restrict__ hin,
    const float* __restrict__ Wl, const float* __restrict__ Wr,
    const float* __restrict__ bl, float* __restrict__ hout) {
    __shared__ float wl_s[BK][D];
    __shared__ float wr_s[BK][D];
    __shared__ float a_s[BK][APAD];
    __shared__ float h_s[BK][APAD];

    int tid = threadIdx.x;
    int tx = tid & 31;   // col group: cols tx*4 .. tx*4+3
    int ty = tid >> 5;   // row group: rows ty*8 .. ty*8+7
    int row0 = blockIdx.x * BM;

    float acc[8][4];
    float4 bv = *((const float4*)(bl + tx * 4));
    #pragma unroll
    for (int r = 0; r < 8; r++) {
        acc[r][0] = bv.x; acc[r][1] = bv.y; acc[r][2] = bv.z; acc[r][3] = bv.w;
    }

    for (int kt = 0; kt < D; kt += BK) {
        #pragma unroll
        for (int i = 0; i < 4; i++) {
            int f4 = tid + i * 256;
            int kk = f4 >> 5;
            int cc = (f4 & 31) * 4;
            *((float4*)&wl_s[kk][cc]) = *((const float4*)(Wl + (size_t)(kt + kk) * D + cc));
            *((float4*)&wr_s[kk][cc]) = *((const float4*)(Wr + (size_t)(kt + kk) * D + cc));
        }
        #pragma unroll
        for (int i = 0; i < 2; i++) {
            int f4 = tid + i * 256;
            int rr = f4 >> 3;
            int kk = (f4 & 7) * 4;
            int grow = min(row0 + rr, N_NODES - 1);
            float4 av = *((const float4*)(agg + (size_t)grow * D + kt + kk));
            a_s[kk + 0][rr] = av.x; a_s[kk + 1][rr] = av.y;
            a_s[kk + 2][rr] = av.z; a_s[kk + 3][rr] = av.w;
            float4 hv = *((const float4*)(hin + (size_t)grow * D + kt + kk));
            h_s[kk + 0][rr] = hv.x; h_s[kk + 1][rr] = hv.y;
            h_s[kk + 2][rr] = hv.z; h_s[kk + 3][rr] = hv.w;
        }
        __syncthreads();
        #pragma unroll
        for (int k = 0; k < BK; k++) {
            float4 wl4 = *((const float4*)&wl_s[k][tx * 4]);
            float4 wr4 = *((const float4*)&wr_s[k][tx * 4]);
            float4 a0 = *((const float4*)&a_s[k][ty * 8]);
            float4 a1 = *((const float4*)&a_s[k][ty * 8 + 4]);
            float4 h0 = *((const float4*)&h_s[k][ty * 8]);
            float4 h1 = *((const float4*)&h_s[k][ty * 8 + 4]);
            float ar[8] = {a0.x, a0.y, a0.z, a0.w, a1.x, a1.y, a1.z, a1.w};
            float hr[8] = {h0.x, h0.y, h0.z, h0.w, h1.x, h1.y, h1.z, h1.w};
            #pragma unroll
            for (int r = 0; r < 8; r++) {
                acc[r][0] += ar[r] * wl4.x; acc[r][0] += hr[r] * wr4.x;
                acc[r][1] += ar[r] * wl4.y; acc[r][1] += hr[r] * wr4.y;
                acc[r][2] += ar[r] * wl4.z; acc[r][2] += hr[r] * wr4.z;
                acc[r][3] += ar[r] * wl4.w; acc[r][3] += hr[r] * wr4.w;
            }
        }
        __syncthreads();
    }
    #pragma unroll
    for (int r = 0; r < 8; r++) {
        int row = row0 + ty * 8 + r;
        if (row < N_NODES) {
            float4 o;
            o.x = fmaxf(acc[r][0], 0.f);
            o.y = fmaxf(acc[r][1], 0.f);
            o.z = fmaxf(acc[r][2], 0.f);
            o.w = fmaxf(acc[r][3], 0.f);
            *((float4*)(hout + (size_t)row * D + tx * 4)) = o;
        }
    }
}

// ---------------- readout: out[i] = h[i] . W_out + b_out ----------------

__global__ void out_kernel(const float* __restrict__ h, const float* __restrict__ Wout,
                           const float* __restrict__ bout, float* __restrict__ out) {
    int node = blockIdx.x * 4 + (threadIdx.x >> 6);
    int lane = threadIdx.x & 63;
    if (node >= N_NODES) return;
    const float* hr = h + (size_t)node * D;
    float v = hr[lane] * Wout[lane] + hr[lane + 64] * Wout[lane + 64];
    #pragma unroll
    for (int off = 32; off > 0; off >>= 1) v += __shfl_down(v, off, 64);
    if (lane == 0) out[node] = v + bout[0];
}

// ---------------- launch ----------------

extern "C" void kernel_launch(void* const* d_in, const int* in_sizes, int n_in,
                              void* d_out, int out_size, void* d_ws, size_t ws_size,
                              hipStream_t stream) {
    const float* x     = (const float*)d_in[0];
    const int*   edge  = (const int*)d_in[1];   // [2, E] flattened: src then dst
    const float* W_l   = (const float*)d_in[2];
    const float* b_l   = (const float*)d_in[3];
    const float* W_r   = (const float*)d_in[4];
    const float* W_out = (const float*)d_in[5];
    const float* b_out = (const float*)d_in[6];
    float* out = (float*)d_out;

    char* ws = (char*)d_ws;
    size_t off = 0;
    auto alloc = [&](size_t bytes) -> void* {
        void* p = ws + off;
        off += (bytes + 255) & ~(size_t)255;
        return p;
    };
    float* h         = (float*)alloc((size_t)N_NODES * D * sizeof(float));
    float* agg       = (float*)alloc((size_t)N_NODES * D * sizeof(float));
    int*   deg       = (int*)alloc((size_t)N_NODES * sizeof(int));
    int*   row_start = (int*)alloc((size_t)(N_NODES + 1) * sizeof(int));
    int*   cursor    = (int*)alloc((size_t)N_NODES * sizeof(int));
    float* inv_deg   = (float*)alloc((size_t)N_NODES * sizeof(float));
    int*   csr_src   = (int*)alloc((size_t)N_EDGES * sizeof(int));
    int*   block_sums= (int*)alloc((size_t)N_SCAN_BLOCKS * sizeof(int));

    const int* src = edge;
    const int* dst = edge + N_EDGES;

    hipMemsetAsync(deg, 0, (size_t)N_NODES * sizeof(int), stream);
    hipMemsetAsync(cursor, 0, (size_t)N_NODES * sizeof(int), stream);

    hist_kernel<<<(N_EDGES + 255) / 256, 256, 0, stream>>>(dst, deg);
    block_sum_kernel<<<N_SCAN_BLOCKS, SCAN_BLOCK, 0, stream>>>(deg, block_sums);
    scan_sums_kernel<<<1, SCAN_BLOCK, 0, stream>>>(block_sums, row_start);
    scan_final_kernel<<<N_SCAN_BLOCKS, SCAN_BLOCK, 0, stream>>>(deg, block_sums, row_start, inv_deg);
    fill_kernel<<<(N_EDGES + 255) / 256, 256, 0, stream>>>(src, dst, row_start, cursor, csr_src);

    const int agg_grid = (N_NODES + 7) / 8;
    const int gemm_grid = (N_NODES + BM - 1) / BM;

    agg_kernel<<<agg_grid, 256, 0, stream>>>(x, row_start, csr_src, inv_deg, agg);
    gemm_kernel<<<gemm_grid, 256, 0, stream>>>(agg, x, W_l, W_r, b_l, h);
    for (int l = 1; l < NLAYERS; l++) {
        agg_kernel<<<agg_grid, 256, 0, stream>>>(h, row_start, csr_src, inv_deg, agg);
        gemm_kernel<<<gemm_grid, 256, 0, stream>>>(agg, h,
            W_l + (size_t)l * D * D, W_r + (size_t)l * D * D, b_l + (size_t)l * D, h);
    }
    out_kernel<<<(N_NODES + 3) / 4, 256, 0, stream>>>(h, W_out, b_out, out);
}

// Round 3
// 342.039 us; speedup vs baseline: 1.6737x; 1.3606x over previous
//
#include <hip/hip_runtime.h>

#define N_NODES 50000
#define N_EDGES 600000
#define D 128
#define NLAYERS 3

#define SCAN_BLOCK 256
#define N_SCAN_BLOCKS ((N_NODES + SCAN_BLOCK - 1) / SCAN_BLOCK)   // 196

typedef __attribute__((ext_vector_type(8))) short short8;
typedef __attribute__((ext_vector_type(4))) float floatx4;

// bf16 helpers (bit-exact unpack, RNE pack)
__device__ __forceinline__ float bf_lo(unsigned u) { return __uint_as_float(u << 16); }
__device__ __forceinline__ float bf_hi(unsigned u) { return __uint_as_float(u & 0xffff0000u); }
__device__ __forceinline__ unsigned short f2bf(float f) {
    unsigned u = __float_as_uint(f);
    return (unsigned short)((u + 0x7fffu + ((u >> 16) & 1u)) >> 16);
}

// ---------------- CSR build ----------------

__global__ void hist_kernel(const int* __restrict__ dst, int* __restrict__ deg) {
    int e = blockIdx.x * blockDim.x + threadIdx.x;
    if (e < N_EDGES) atomicAdd(&deg[dst[e]], 1);
}

__global__ void block_sum_kernel(const int* __restrict__ deg, int* __restrict__ block_sums) {
    int tid = threadIdx.x;
    int i = blockIdx.x * SCAN_BLOCK + tid;
    int v = (i < N_NODES) ? deg[i] : 0;
    #pragma unroll
    for (int off = 32; off > 0; off >>= 1) v += __shfl_down(v, off, 64);
    __shared__ int wsum[4];
    if ((tid & 63) == 0) wsum[tid >> 6] = v;
    __syncthreads();
    if (tid == 0) block_sums[blockIdx.x] = wsum[0] + wsum[1] + wsum[2] + wsum[3];
}

__global__ void scan_sums_kernel(int* __restrict__ block_sums, int* __restrict__ row_start) {
    __shared__ int s[SCAN_BLOCK];
    int tid = threadIdx.x;
    int v = (tid < N_SCAN_BLOCKS) ? block_sums[tid] : 0;
    s[tid] = v;
    __syncthreads();
    #pragma unroll
    for (int off = 1; off < SCAN_BLOCK; off <<= 1) {
        int t = (tid >= off) ? s[tid - off] : 0;
        __syncthreads();
        s[tid] += t;
        __syncthreads();
    }
    if (tid < N_SCAN_BLOCKS) block_sums[tid] = s[tid] - v;
    if (tid == SCAN_BLOCK - 1) row_start[N_NODES] = s[SCAN_BLOCK - 1];
}

__global__ void scan_final_kernel(const int* __restrict__ deg, const int* __restrict__ block_sums,
                                  int* __restrict__ row_start, float* __restrict__ inv_deg) {
    __shared__ int s[SCAN_BLOCK];
    int tid = threadIdx.x;
    int i = blockIdx.x * SCAN_BLOCK + tid;
    int v = (i < N_NODES) ? deg[i] : 0;
    s[tid] = v;
    __syncthreads();
    #pragma unroll
    for (int off = 1; off < SCAN_BLOCK; off <<= 1) {
        int t = (tid >= off) ? s[tid - off] : 0;
        __syncthreads();
        s[tid] += t;
        __syncthreads();
    }
    if (i < N_NODES) {
        row_start[i] = s[tid] - v + block_sums[blockIdx.x];
        inv_deg[i] = 1.0f / fmaxf((float)v, 1.0f);
    }
}

__global__ void fill_kernel(const int* __restrict__ src, const int* __restrict__ dst,
                            const int* __restrict__ row_start, int* __restrict__ cursor,
                            int* __restrict__ csr_src) {
    int e = blockIdx.x * blockDim.x + threadIdx.x;
    if (e < N_EDGES) {
        int d_ = dst[e];
        int pos = atomicAdd(&cursor[d_], 1);
        csr_src[row_start[d_] + pos] = src[e];
    }
}

// ---------------- conversions ----------------

// x (fp32 [N,128]) -> bf16
__global__ void cvt_x_kernel(const float* __restrict__ x, unsigned short* __restrict__ xb) {
    int i = blockIdx.x * blockDim.x + threadIdx.x;   // one float4 per thread
    if (i >= N_NODES * D / 4) return;
    float4 v = ((const float4*)x)[i];
    ushort4 o;
    o.x = f2bf(v.x); o.y = f2bf(v.y); o.z = f2bf(v.z); o.w = f2bf(v.w);
    ((ushort4*)xb)[i] = o;
}

// Wt[l][n][k] = bf16( k<128 ? Wl[l][k][n] : Wr[l][k-128][n] ), [3][128][256]
__global__ void cvt_w_kernel(const float* __restrict__ Wl, const float* __restrict__ Wr,
                             unsigned short* __restrict__ Wt) {
    int t = blockIdx.x * blockDim.x + threadIdx.x;
    if (t >= NLAYERS * D * 256) return;
    int l = t / (D * 256);
    int rem = t - l * (D * 256);
    int n = rem >> 8;
    int k = rem & 255;
    float v = (k < D) ? Wl[(size_t)l * D * D + (size_t)k * D + n]
                      : Wr[(size_t)l * D * D + (size_t)(k - D) * D + n];
    Wt[t] = f2bf(v);
}

// ---------------- mean aggregation (bf16 gather, fp32 accumulate) ----------------
// 16 lanes per node (8 bf16 = 16B per lane), 16 nodes per 256-thread block.

__global__ void agg_kernel(const unsigned short* __restrict__ h, const int* __restrict__ row_start,
                           const int* __restrict__ csr_src, const float* __restrict__ inv_deg,
                           unsigned short* __restrict__ agg) {
    int node = blockIdx.x * 16 + (threadIdx.x >> 4);
    int q = threadIdx.x & 15;
    if (node >= N_NODES) return;
    int beg = row_start[node], end = row_start[node + 1];
    float acc[8] = {0.f, 0.f, 0.f, 0.f, 0.f, 0.f, 0.f, 0.f};
    for (int e = beg; e < end; e++) {
        int s = csr_src[e];
        uint4 v = *((const uint4*)(h + (size_t)s * D + q * 8));
        acc[0] += bf_lo(v.x); acc[1] += bf_hi(v.x);
        acc[2] += bf_lo(v.y); acc[3] += bf_hi(v.y);
        acc[4] += bf_lo(v.z); acc[5] += bf_hi(v.z);
        acc[6] += bf_lo(v.w); acc[7] += bf_hi(v.w);
    }
    float w = inv_deg[node];
    uint4 o;
    o.x = (unsigned)f2bf(acc[0] * w) | ((unsigned)f2bf(acc[1] * w) << 16);
    o.y = (unsigned)f2bf(acc[2] * w) | ((unsigned)f2bf(acc[3] * w) << 16);
    o.z = (unsigned)f2bf(acc[4] * w) | ((unsigned)f2bf(acc[5] * w) << 16);
    o.w = (unsigned)f2bf(acc[6] * w) | ((unsigned)f2bf(acc[7] * w) << 16);
    *((uint4*)(agg + (size_t)node * D + q * 8)) = o;
}

// ---------------- MFMA GEMM: hout = relu([agg|hin](bf16) @ Wt^T + bias) ----------------
// One wave per block, 32 rows x 128 cols, K=256. Zero LDS, zero barriers.
// A frag: A[m][k], m=lane&15, k=quad*8+j. B frag: B[k][n], n=lane&15, k=quad*8+j.
// C/D: col=lane&15, row=quad*4+reg.

__global__ __launch_bounds__(64) void gemm_mfma_kernel(
    const unsigned short* __restrict__ aggb, const unsigned short* __restrict__ hinb,
    const unsigned short* __restrict__ Wt, const float* __restrict__ bias,
    unsigned short* __restrict__ hout) {
    int m0 = blockIdx.x * 32;
    int lane = threadIdx.x;
    int half = lane & 15;
    int quad = lane >> 4;
    int kq = quad * 8;

    floatx4 acc[2][8];
    #pragma unroll
    for (int mt = 0; mt < 2; mt++)
        #pragma unroll
        for (int j = 0; j < 8; j++)
            acc[mt][j] = (floatx4){0.f, 0.f, 0.f, 0.f};

    int r0 = min(m0 + half, N_NODES - 1);
    int r1 = min(m0 + 16 + half, N_NODES - 1);

    #pragma unroll
    for (int kt = 0; kt < 8; kt++) {
        const unsigned short* abase = (kt < 4) ? aggb : hinb;
        int ka = (kt & 3) * 32 + kq;          // k within the 128-wide source
        int kw = kt * 32 + kq;                // k within Wt's 256-wide K
        short8 a0 = *((const short8*)(abase + (size_t)r0 * D + ka));
        short8 a1 = *((const short8*)(abase + (size_t)r1 * D + ka));
        #pragma unroll
        for (int j = 0; j < 8; j++) {
            short8 b = *((const short8*)(Wt + (size_t)(j * 16 + half) * 256 + kw));
            acc[0][j] = __builtin_amdgcn_mfma_f32_16x16x32_bf16(a0, b, acc[0][j], 0, 0, 0);
            acc[1][j] = __builtin_amdgcn_mfma_f32_16x16x32_bf16(a1, b, acc[1][j], 0, 0, 0);
        }
    }

    #pragma unroll
    for (int j = 0; j < 8; j++) {
        int col = j * 16 + half;
        float bv = bias[col];
        #pragma unroll
        for (int mt = 0; mt < 2; mt++) {
            #pragma unroll
            for (int r = 0; r < 4; r++) {
                int row = m0 + mt * 16 + quad * 4 + r;
                if (row < N_NODES) {
                    float v = fmaxf(acc[mt][j][r] + bv, 0.f);
                    hout[(size_t)row * D + col] = f2bf(v);
                }
            }
        }
    }
}

// ---------------- readout: out[i] = h[i] . W_out + b_out ----------------

__global__ void out_kernel(const unsigned short* __restrict__ h, const float* __restrict__ Wout,
                           const float* __restrict__ bout, float* __restrict__ out) {
    int node = blockIdx.x * 4 + (threadIdx.x >> 6);
    int lane = threadIdx.x & 63;
    if (node >= N_NODES) return;
    unsigned u = *((const unsigned*)(h + (size_t)node * D + lane * 2));
    float v = bf_lo(u) * Wout[2 * lane] + bf_hi(u) * Wout[2 * lane + 1];
    #pragma unroll
    for (int off = 32; off > 0; off >>= 1) v += __shfl_down(v, off, 64);
    if (lane == 0) out[node] = v + bout[0];
}

// ---------------- launch ----------------

extern "C" void kernel_launch(void* const* d_in, const int* in_sizes, int n_in,
                              void* d_out, int out_size, void* d_ws, size_t ws_size,
                              hipStream_t stream) {
    const float* x     = (const float*)d_in[0];
    const int*   edge  = (const int*)d_in[1];   // [2, E]: src then dst
    const float* W_l   = (const float*)d_in[2];
    const float* b_l   = (const float*)d_in[3];
    const float* W_r   = (const float*)d_in[4];
    const float* W_out = (const float*)d_in[5];
    const float* b_out = (const float*)d_in[6];
    float* out = (float*)d_out;

    char* ws = (char*)d_ws;
    size_t off = 0;
    auto alloc = [&](size_t bytes) -> void* {
        void* p = ws + off;
        off += (bytes + 255) & ~(size_t)255;
        return p;
    };
    unsigned short* xb        = (unsigned short*)alloc((size_t)N_NODES * D * 2);
    unsigned short* hb        = (unsigned short*)alloc((size_t)N_NODES * D * 2);
    unsigned short* aggb      = (unsigned short*)alloc((size_t)N_NODES * D * 2);
    unsigned short* Wt        = (unsigned short*)alloc((size_t)NLAYERS * D * 256 * 2);
    int*   deg       = (int*)alloc((size_t)N_NODES * sizeof(int));
    int*   row_start = (int*)alloc((size_t)(N_NODES + 1) * sizeof(int));
    int*   cursor    = (int*)alloc((size_t)N_NODES * sizeof(int));
    float* inv_deg   = (float*)alloc((size_t)N_NODES * sizeof(float));
    int*   csr_src   = (int*)alloc((size_t)N_EDGES * sizeof(int));
    int*   block_sums= (int*)alloc((size_t)N_SCAN_BLOCKS * sizeof(int));

    const int* src = edge;
    const int* dst = edge + N_EDGES;

    hipMemsetAsync(deg, 0, (size_t)N_NODES * sizeof(int), stream);
    hipMemsetAsync(cursor, 0, (size_t)N_NODES * sizeof(int), stream);

    hist_kernel<<<(N_EDGES + 255) / 256, 256, 0, stream>>>(dst, deg);
    block_sum_kernel<<<N_SCAN_BLOCKS, SCAN_BLOCK, 0, stream>>>(deg, block_sums);
    scan_sums_kernel<<<1, SCAN_BLOCK, 0, stream>>>(block_sums, row_start);
    scan_final_kernel<<<N_SCAN_BLOCKS, SCAN_BLOCK, 0, stream>>>(deg, block_sums, row_start, inv_deg);
    fill_kernel<<<(N_EDGES + 255) / 256, 256, 0, stream>>>(src, dst, row_start, cursor, csr_src);

    cvt_x_kernel<<<(N_NODES * D / 4 + 255) / 256, 256, 0, stream>>>(x, xb);
    cvt_w_kernel<<<(NLAYERS * D * 256 + 255) / 256, 256, 0, stream>>>(W_l, W_r, Wt);

    const int agg_grid  = (N_NODES + 15) / 16;
    const int gemm_grid = (N_NODES + 31) / 32;

    agg_kernel<<<agg_grid, 256, 0, stream>>>(xb, row_start, csr_src, inv_deg, aggb);
    gemm_mfma_kernel<<<gemm_grid, 64, 0, stream>>>(aggb, xb, Wt, b_l, hb);
    for (int l = 1; l < NLAYERS; l++) {
        agg_kernel<<<agg_grid, 256, 0, stream>>>(hb, row_start, csr_src, inv_deg, aggb);
        gemm_mfma_kernel<<<gemm_grid, 64, 0, stream>>>(aggb, hb,
            Wt + (size_t)l * D * 256, b_l + (size_t)l * D, hb);
    }
    out_kernel<<<(N_NODES + 3) / 4, 256, 0, stream>>>(hb, W_out, b_out, out);
}

// Round 5
// 324.538 us; speedup vs baseline: 1.7639x; 1.0539x over previous
//
#include <hip/hip_runtime.h>

#define N_NODES 50000
#define N_EDGES 600000
#define D 128
#define NLAYERS 3

#define SCAN_BLOCK 256
#define N_SCAN_BLOCKS ((N_NODES + SCAN_BLOCK - 1) / SCAN_BLOCK)   // 196

typedef __attribute__((ext_vector_type(8))) short short8;
typedef __attribute__((ext_vector_type(4))) float floatx4;

__device__ __forceinline__ float bf_lo(unsigned u) { return __uint_as_float(u << 16); }
__device__ __forceinline__ float bf_hi(unsigned u) { return __uint_as_float(u & 0xffff0000u); }
__device__ __forceinline__ unsigned short f2bf(float f) {
    unsigned u = __float_as_uint(f);
    return (unsigned short)((u + 0x7fffu + ((u >> 16) & 1u)) >> 16);
}

// ---------------- init: zero deg + cursor (replaces 2 memset nodes) ----------------

__global__ void init_kernel(int* __restrict__ deg, int* __restrict__ cursor) {
    int i = blockIdx.x * blockDim.x + threadIdx.x;
    if (i < N_NODES) { deg[i] = 0; cursor[i] = 0; }
}

// ---------------- CSR build (verbatim from passing R2) ----------------

__global__ void hist_kernel(const int* __restrict__ dst, int* __restrict__ deg) {
    int e = blockIdx.x * blockDim.x + threadIdx.x;
    if (e < N_EDGES) atomicAdd(&deg[dst[e]], 1);
}

__global__ void block_sum_kernel(const int* __restrict__ deg, int* __restrict__ block_sums) {
    int tid = threadIdx.x;
    int i = blockIdx.x * SCAN_BLOCK + tid;
    int v = (i < N_NODES) ? deg[i] : 0;
    #pragma unroll
    for (int off = 32; off > 0; off >>= 1) v += __shfl_down(v, off, 64);
    __shared__ int wsum[4];
    if ((tid & 63) == 0) wsum[tid >> 6] = v;
    __syncthreads();
    if (tid == 0) block_sums[blockIdx.x] = wsum[0] + wsum[1] + wsum[2] + wsum[3];
}

__global__ void scan_sums_kernel(int* __restrict__ block_sums, int* __restrict__ row_start) {
    __shared__ int s[SCAN_BLOCK];
    int tid = threadIdx.x;
    int v = (tid < N_SCAN_BLOCKS) ? block_sums[tid] : 0;
    s[tid] = v;
    __syncthreads();
    #pragma unroll
    for (int off = 1; off < SCAN_BLOCK; off <<= 1) {
        int t = (tid >= off) ? s[tid - off] : 0;
        __syncthreads();
        s[tid] += t;
        __syncthreads();
    }
    if (tid < N_SCAN_BLOCKS) block_sums[tid] = s[tid] - v;
    if (tid == SCAN_BLOCK - 1) row_start[N_NODES] = s[SCAN_BLOCK - 1];
}

__global__ void scan_final_kernel(const int* __restrict__ deg, const int* __restrict__ block_sums,
                                  int* __restrict__ row_start, float* __restrict__ inv_deg) {
    __shared__ int s[SCAN_BLOCK];
    int tid = threadIdx.x;
    int i = blockIdx.x * SCAN_BLOCK + tid;
    int v = (i < N_NODES) ? deg[i] : 0;
    s[tid] = v;
    __syncthreads();
    #pragma unroll
    for (int off = 1; off < SCAN_BLOCK; off <<= 1) {
        int t = (tid >= off) ? s[tid - off] : 0;
        __syncthreads();
        s[tid] += t;
        __syncthreads();
    }
    if (i < N_NODES) {
        row_start[i] = s[tid] - v + block_sums[blockIdx.x];
        inv_deg[i] = 1.0f / fmaxf((float)v, 1.0f);
    }
}

__global__ void fill_kernel(const int* __restrict__ src, const int* __restrict__ dst,
                            const int* __restrict__ row_start, int* __restrict__ cursor,
                            int* __restrict__ csr_src) {
    int e = blockIdx.x * blockDim.x + threadIdx.x;
    if (e < N_EDGES) {
        int d_ = dst[e];
        int pos = atomicAdd(&cursor[d_], 1);
        csr_src[row_start[d_] + pos] = src[e];
    }
}

// ---------------- merged conversions: x->bf16 and Wt build ----------------
// section A: i in [0, 1600000): one float4 of x -> ushort4 of xb
// section B: i in [1600000, 1600000+98304): one element of Wt

#define CVT_A (N_NODES * D / 4)              // 1,600,000
#define CVT_B (NLAYERS * D * 256)            // 98,304
#define CVT_TOTAL (CVT_A + CVT_B)

__global__ void cvt_all_kernel(const float* __restrict__ x, const float* __restrict__ Wl,
                               const float* __restrict__ Wr,
                               unsigned short* __restrict__ xb, unsigned short* __restrict__ Wt) {
    int i = blockIdx.x * blockDim.x + threadIdx.x;
    if (i < CVT_A) {
        float4 v = ((const float4*)x)[i];
        ushort4 o;
        o.x = f2bf(v.x); o.y = f2bf(v.y); o.z = f2bf(v.z); o.w = f2bf(v.w);
        ((ushort4*)xb)[i] = o;
    } else if (i < CVT_TOTAL) {
        int t = i - CVT_A;
        int l = t / (D * 256);
        int rem = t - l * (D * 256);
        int n = rem >> 8;
        int k = rem & 255;
        float v = (k < D) ? Wl[(size_t)l * D * D + (size_t)k * D + n]
                          : Wr[(size_t)l * D * D + (size_t)(k - D) * D + n];
        Wt[t] = f2bf(v);
    }
}

// ---------------- mean aggregation (verbatim from passing R2) ----------------

__global__ void agg_kernel(const unsigned short* __restrict__ h, const int* __restrict__ row_start,
                           const int* __restrict__ csr_src, const float* __restrict__ inv_deg,
                           unsigned short* __restrict__ agg) {
    int node = blockIdx.x * 16 + (threadIdx.x >> 4);
    int q = threadIdx.x & 15;
    if (node >= N_NODES) return;
    int beg = row_start[node], end = row_start[node + 1];
    float acc[8] = {0.f, 0.f, 0.f, 0.f, 0.f, 0.f, 0.f, 0.f};
    for (int e = beg; e < end; e++) {
        int s = csr_src[e];
        uint4 v = *((const uint4*)(h + (size_t)s * D + q * 8));
        acc[0] += bf_lo(v.x); acc[1] += bf_hi(v.x);
        acc[2] += bf_lo(v.y); acc[3] += bf_hi(v.y);
        acc[4] += bf_lo(v.z); acc[5] += bf_hi(v.z);
        acc[6] += bf_lo(v.w); acc[7] += bf_hi(v.w);
    }
    float w = inv_deg[node];
    uint4 o;
    o.x = (unsigned)f2bf(acc[0] * w) | ((unsigned)f2bf(acc[1] * w) << 16);
    o.y = (unsigned)f2bf(acc[2] * w) | ((unsigned)f2bf(acc[3] * w) << 16);
    o.z = (unsigned)f2bf(acc[4] * w) | ((unsigned)f2bf(acc[5] * w) << 16);
    o.w = (unsigned)f2bf(acc[6] * w) | ((unsigned)f2bf(acc[7] * w) << 16);
    *((uint4*)(agg + (size_t)node * D + q * 8)) = o;
}

// ---------------- MFMA GEMM (verbatim from passing R2) ----------------
// One wave per block, 32 rows x 128 cols, K=256. Zero LDS, zero barriers.

__global__ __launch_bounds__(64) void gemm_mfma_kernel(
    const unsigned short* __restrict__ aggb, const unsigned short* __restrict__ hinb,
    const unsigned short* __restrict__ Wt, const float* __restrict__ bias,
    unsigned short* __restrict__ hout) {
    int m0 = blockIdx.x * 32;
    int lane = threadIdx.x;
    int half = lane & 15;
    int quad = lane >> 4;
    int kq = quad * 8;

    floatx4 acc[2][8];
    #pragma unroll
    for (int mt = 0; mt < 2; mt++)
        #pragma unroll
        for (int j = 0; j < 8; j++)
            acc[mt][j] = (floatx4){0.f, 0.f, 0.f, 0.f};

    int r0 = min(m0 + half, N_NODES - 1);
    int r1 = min(m0 + 16 + half, N_NODES - 1);

    #pragma unroll
    for (int kt = 0; kt < 8; kt++) {
        const unsigned short* abase = (kt < 4) ? aggb : hinb;
        int ka = (kt & 3) * 32 + kq;
        int kw = kt * 32 + kq;
        short8 a0 = *((const short8*)(abase + (size_t)r0 * D + ka));
        short8 a1 = *((const short8*)(abase + (size_t)r1 * D + ka));
        #pragma unroll
        for (int j = 0; j < 8; j++) {
            short8 b = *((const short8*)(Wt + (size_t)(j * 16 + half) * 256 + kw));
            acc[0][j] = __builtin_amdgcn_mfma_f32_16x16x32_bf16(a0, b, acc[0][j], 0, 0, 0);
            acc[1][j] = __builtin_amdgcn_mfma_f32_16x16x32_bf16(a1, b, acc[1][j], 0, 0, 0);
        }
    }

    #pragma unroll
    for (int j = 0; j < 8; j++) {
        int col = j * 16 + half;
        float bv = bias[col];
        #pragma unroll
        for (int mt = 0; mt < 2; mt++) {
            #pragma unroll
            for (int r = 0; r < 4; r++) {
                int row = m0 + mt * 16 + quad * 4 + r;
                if (row < N_NODES)
                    hout[(size_t)row * D + col] = f2bf(fmaxf(acc[mt][j][r] + bv, 0.f));
            }
        }
    }
}

// ---------------- last layer: same GEMM, epilogue fused with readout ----------------

__global__ __launch_bounds__(64) void gemm_mfma_out_kernel(
    const unsigned short* __restrict__ aggb, const unsigned short* __restrict__ hinb,
    const unsigned short* __restrict__ Wt, const float* __restrict__ bias,
    const float* __restrict__ Wout, const float* __restrict__ bout,
    float* __restrict__ out) {
    int m0 = blockIdx.x * 32;
    int lane = threadIdx.x;
    int half = lane & 15;
    int quad = lane >> 4;
    int kq = quad * 8;

    floatx4 acc[2][8];
    #pragma unroll
    for (int mt = 0; mt < 2; mt++)
        #pragma unroll
        for (int j = 0; j < 8; j++)
            acc[mt][j] = (floatx4){0.f, 0.f, 0.f, 0.f};

    int r0 = min(m0 + half, N_NODES - 1);
    int r1 = min(m0 + 16 + half, N_NODES - 1);

    #pragma unroll
    for (int kt = 0; kt < 8; kt++) {
        const unsigned short* abase = (kt < 4) ? aggb : hinb;
        int ka = (kt & 3) * 32 + kq;
        int kw = kt * 32 + kq;
        short8 a0 = *((const short8*)(abase + (size_t)r0 * D + ka));
        short8 a1 = *((const short8*)(abase + (size_t)r1 * D + ka));
        #pragma unroll
        for (int j = 0; j < 8; j++) {
            short8 b = *((const short8*)(Wt + (size_t)(j * 16 + half) * 256 + kw));
            acc[0][j] = __builtin_amdgcn_mfma_f32_16x16x32_bf16(a0, b, acc[0][j], 0, 0, 0);
            acc[1][j] = __builtin_amdgcn_mfma_f32_16x16x32_bf16(a1, b, acc[1][j], 0, 0, 0);
        }
    }

    float vout[2][4] = {{0.f, 0.f, 0.f, 0.f}, {0.f, 0.f, 0.f, 0.f}};
    #pragma unroll
    for (int j = 0; j < 8; j++) {
        int col = j * 16 + half;
        float bv = bias[col];
        float wv = Wout[col];
        #pragma unroll
        for (int mt = 0; mt < 2; mt++)
            #pragma unroll
            for (int r = 0; r < 4; r++)
                vout[mt][r] += fmaxf(acc[mt][j][r] + bv, 0.f) * wv;
    }
    #pragma unroll
    for (int off = 1; off < 16; off <<= 1) {
        #pragma unroll
        for (int mt = 0; mt < 2; mt++)
            #pragma unroll
            for (int r = 0; r < 4; r++)
                vout[mt][r] += __shfl_xor(vout[mt][r], off, 64);
    }
    if (half == 0) {
        float bo = bout[0];
        #pragma unroll
        for (int mt = 0; mt < 2; mt++) {
            #pragma unroll
            for (int r = 0; r < 4; r++) {
                int row = m0 + mt * 16 + quad * 4 + r;
                if (row < N_NODES) out[row] = vout[mt][r] + bo;
            }
        }
    }
}

// ---------------- launch ----------------

extern "C" void kernel_launch(void* const* d_in, const int* in_sizes, int n_in,
                              void* d_out, int out_size, void* d_ws, size_t ws_size,
                              hipStream_t stream) {
    const float* x     = (const float*)d_in[0];
    const int*   edge  = (const int*)d_in[1];   // [2, E]: src then dst
    const float* W_l   = (const float*)d_in[2];
    const float* b_l   = (const float*)d_in[3];
    const float* W_r   = (const float*)d_in[4];
    const float* W_out = (const float*)d_in[5];
    const float* b_out = (const float*)d_in[6];
    float* out = (float*)d_out;

    char* ws = (char*)d_ws;
    size_t off = 0;
    auto alloc = [&](size_t bytes) -> void* {
        void* p = ws + off;
        off += (bytes + 255) & ~(size_t)255;
        return p;
    };
    unsigned short* xb   = (unsigned short*)alloc((size_t)N_NODES * D * 2);
    unsigned short* hb   = (unsigned short*)alloc((size_t)N_NODES * D * 2);
    unsigned short* aggb = (unsigned short*)alloc((size_t)N_NODES * D * 2);
    unsigned short* Wt   = (unsigned short*)alloc((size_t)NLAYERS * D * 256 * 2);
    int*   deg        = (int*)alloc((size_t)N_NODES * sizeof(int));
    int*   row_start  = (int*)alloc((size_t)(N_NODES + 1) * sizeof(int));
    int*   cursor     = (int*)alloc((size_t)N_NODES * sizeof(int));
    float* inv_deg    = (float*)alloc((size_t)N_NODES * sizeof(float));
    int*   csr_src    = (int*)alloc((size_t)N_EDGES * sizeof(int));
    int*   block_sums = (int*)alloc((size_t)N_SCAN_BLOCKS * sizeof(int));

    const int* src = edge;
    const int* dst = edge + N_EDGES;

    init_kernel<<<(N_NODES + 255) / 256, 256, 0, stream>>>(deg, cursor);
    hist_kernel<<<(N_EDGES + 255) / 256, 256, 0, stream>>>(dst, deg);
    block_sum_kernel<<<N_SCAN_BLOCKS, SCAN_BLOCK, 0, stream>>>(deg, block_sums);
    scan_sums_kernel<<<1, SCAN_BLOCK, 0, stream>>>(block_sums, row_start);
    scan_final_kernel<<<N_SCAN_BLOCKS, SCAN_BLOCK, 0, stream>>>(deg, block_sums, row_start, inv_deg);
    fill_kernel<<<(N_EDGES + 255) / 256, 256, 0, stream>>>(src, dst, row_start, cursor, csr_src);

    cvt_all_kernel<<<(CVT_TOTAL + 255) / 256, 256, 0, stream>>>(x, W_l, W_r, xb, Wt);

    const int agg_grid  = (N_NODES + 15) / 16;
    const int gemm_grid = (N_NODES + 31) / 32;

    // layer 0: xb -> hb
    agg_kernel<<<agg_grid, 256, 0, stream>>>(xb, row_start, csr_src, inv_deg, aggb);
    gemm_mfma_kernel<<<gemm_grid, 64, 0, stream>>>(aggb, xb, Wt, b_l, hb);
    // layer 1: hb -> hb (in-place, row-exclusive)
    agg_kernel<<<agg_grid, 256, 0, stream>>>(hb, row_start, csr_src, inv_deg, aggb);
    gemm_mfma_kernel<<<gemm_grid, 64, 0, stream>>>(aggb, hb,
        Wt + (size_t)1 * D * 256, b_l + 1 * D, hb);
    // layer 2: hb -> out (readout fused)
    agg_kernel<<<agg_grid, 256, 0, stream>>>(hb, row_start, csr_src, inv_deg, aggb);
    gemm_mfma_out_kernel<<<gemm_grid, 64, 0, stream>>>(aggb, hb,
        Wt + (size_t)2 * D * 256, b_l + 2 * D, W_out, b_out, out);
}

// Round 6
// 294.089 us; speedup vs baseline: 1.9465x; 1.1035x over previous
//
#include <hip/hip_runtime.h>

#define N_NODES 50000
#define N_EDGES 600000
#define D 128
#define NLAYERS 3

typedef __attribute__((ext_vector_type(8))) short short8;
typedef __attribute__((ext_vector_type(4))) float floatx4;

__device__ __forceinline__ float bf_lo(unsigned u) { return __uint_as_float(u << 16); }
__device__ __forceinline__ float bf_hi(unsigned u) { return __uint_as_float(u & 0xffff0000u); }
__device__ __forceinline__ unsigned short f2bf(float f) {
    unsigned u = __float_as_uint(f);
    return (unsigned short)((u + 0x7fffu + ((u >> 16) & 1u)) >> 16);
}

// ---------------- merged: x->bf16, Wt fragment-layout build, zero-init ----------------
// section A: [0, CVT_A)           one float4 of x -> ushort4 of xb
// section B: [CVT_A, +CVT_B)      one bf16 element of WtF (MFMA B-fragment order)
// section C: [+CVT_B, +N_NODES)   zero deg/cursor (+ counter at j==0)

#define CVT_A (N_NODES * D / 4)              // 1,600,000
#define CVT_B (NLAYERS * D * 256)            // 98,304
#define CVT_TOTAL (CVT_A + CVT_B + N_NODES)

// WtF per layer: 4096 short8 fragments; frag index f=(j*8+kt)*64+lane, lane=quad*16+half.
// element i of fragment = W^T[n=j*16+half][k=kt*32+quad*8+i]; W^T[n][k]=(k<128?Wl[k][n]:Wr[k-128][n])
__global__ void cvt_init_kernel(const float* __restrict__ x, const float* __restrict__ Wl,
                                const float* __restrict__ Wr,
                                unsigned short* __restrict__ xb, unsigned short* __restrict__ WtF,
                                int* __restrict__ deg, int* __restrict__ cursor,
                                int* __restrict__ counter) {
    int i = blockIdx.x * blockDim.x + threadIdx.x;
    if (i < CVT_A) {
        float4 v = ((const float4*)x)[i];
        ushort4 o;
        o.x = f2bf(v.x); o.y = f2bf(v.y); o.z = f2bf(v.z); o.w = f2bf(v.w);
        ((ushort4*)xb)[i] = o;
    } else if (i < CVT_A + CVT_B) {
        int t = i - CVT_A;
        int l = t >> 15;                 // /32768 (=128*256)
        int r = t & 32767;
        int f = r >> 3;
        int ii = r & 7;
        int jkt = f >> 6;
        int lane = f & 63;
        int j = jkt >> 3;
        int kt = jkt & 7;
        int half = lane & 15;
        int quad = lane >> 4;
        int n = j * 16 + half;
        int k = kt * 32 + quad * 8 + ii;
        float v = (k < D) ? Wl[(size_t)l * D * D + (size_t)k * D + n]
                          : Wr[(size_t)l * D * D + (size_t)(k - D) * D + n];
        WtF[t] = f2bf(v);
    } else if (i < CVT_TOTAL) {
        int j = i - (CVT_A + CVT_B);
        deg[j] = 0;
        cursor[j] = 0;
        if (j == 0) counter[0] = 0;
    }
}

// ---------------- CSR build ----------------

__global__ void hist_kernel(const int* __restrict__ dst, int* __restrict__ deg) {
    int e = blockIdx.x * blockDim.x + threadIdx.x;
    if (e < N_EDGES) atomicAdd(&deg[dst[e]], 1);
}

// row_start via per-wave scan + one atomicAdd per wave (order-free allocation)
__global__ void alloc_kernel(const int* __restrict__ deg, int* __restrict__ counter,
                             int* __restrict__ row_start, float* __restrict__ inv_deg) {
    int i = blockIdx.x * blockDim.x + threadIdx.x;
    int lane = threadIdx.x & 63;
    int d = (i < N_NODES) ? deg[i] : 0;
    int v = d;
    #pragma unroll
    for (int off = 1; off < 64; off <<= 1) {
        int t = __shfl_up(v, off, 64);
        if (lane >= off) v += t;
    }
    int total = __shfl(v, 63, 64);
    int base = 0;
    if (lane == 63) base = atomicAdd(counter, total);
    base = __shfl(base, 63, 64);
    if (i < N_NODES) {
        row_start[i] = base + v - d;
        inv_deg[i] = 1.0f / fmaxf((float)d, 1.0f);
    }
}

__global__ void fill_kernel(const int* __restrict__ src, const int* __restrict__ dst,
                            const int* __restrict__ row_start, int* __restrict__ cursor,
                            int* __restrict__ csr_src) {
    int e = blockIdx.x * blockDim.x + threadIdx.x;
    if (e < N_EDGES) {
        int d_ = dst[e];
        int pos = atomicAdd(&cursor[d_], 1);
        csr_src[row_start[d_] + pos] = src[e];
    }
}

// ---------------- mean aggregation (bf16 gather, fp32 acc, unroll x2) ----------------
// 16 nodes per 256-thread block; 16 lanes per node, 16B per lane.

__global__ void agg_kernel(const unsigned short* __restrict__ h, const int* __restrict__ row_start,
                           const int* __restrict__ deg, const int* __restrict__ csr_src,
                           const float* __restrict__ inv_deg, unsigned short* __restrict__ agg) {
    int node = blockIdx.x * 16 + (threadIdx.x >> 4);
    int q = threadIdx.x & 15;
    if (node >= N_NODES) return;
    int beg = row_start[node];
    int end = beg + deg[node];
    float a[8] = {0.f, 0.f, 0.f, 0.f, 0.f, 0.f, 0.f, 0.f};
    float b[8] = {0.f, 0.f, 0.f, 0.f, 0.f, 0.f, 0.f, 0.f};
    int e = beg;
    for (; e + 2 <= end; e += 2) {
        int s0 = csr_src[e];
        int s1 = csr_src[e + 1];
        uint4 v0 = *((const uint4*)(h + (size_t)s0 * D + q * 8));
        uint4 v1 = *((const uint4*)(h + (size_t)s1 * D + q * 8));
        a[0] += bf_lo(v0.x); a[1] += bf_hi(v0.x);
        a[2] += bf_lo(v0.y); a[3] += bf_hi(v0.y);
        a[4] += bf_lo(v0.z); a[5] += bf_hi(v0.z);
        a[6] += bf_lo(v0.w); a[7] += bf_hi(v0.w);
        b[0] += bf_lo(v1.x); b[1] += bf_hi(v1.x);
        b[2] += bf_lo(v1.y); b[3] += bf_hi(v1.y);
        b[4] += bf_lo(v1.z); b[5] += bf_hi(v1.z);
        b[6] += bf_lo(v1.w); b[7] += bf_hi(v1.w);
    }
    if (e < end) {
        int s0 = csr_src[e];
        uint4 v0 = *((const uint4*)(h + (size_t)s0 * D + q * 8));
        a[0] += bf_lo(v0.x); a[1] += bf_hi(v0.x);
        a[2] += bf_lo(v0.y); a[3] += bf_hi(v0.y);
        a[4] += bf_lo(v0.z); a[5] += bf_hi(v0.z);
        a[6] += bf_lo(v0.w); a[7] += bf_hi(v0.w);
    }
    float w = inv_deg[node];
    uint4 o;
    o.x = (unsigned)f2bf((a[0] + b[0]) * w) | ((unsigned)f2bf((a[1] + b[1]) * w) << 16);
    o.y = (unsigned)f2bf((a[2] + b[2]) * w) | ((unsigned)f2bf((a[3] + b[3]) * w) << 16);
    o.z = (unsigned)f2bf((a[4] + b[4]) * w) | ((unsigned)f2bf((a[5] + b[5]) * w) << 16);
    o.w = (unsigned)f2bf((a[6] + b[6]) * w) | ((unsigned)f2bf((a[7] + b[7]) * w) << 16);
    *((uint4*)(agg + (size_t)node * D + q * 8)) = o;
}

// ---------------- MFMA GEMM: hout = relu([agg|hin](bf16) @ W^T + bias) ----------------
// One wave per block, 32 rows x 128 cols, K=256. B from fragment-layout WtF (coalesced).
// Epilogue: LDS C-tile transpose -> coalesced uint4 row-major stores.

#define CPITCH 136   // shorts; 272B row pitch (16B-aligned, breaks quad bank aliasing)

__global__ __launch_bounds__(64) void gemm_mfma_kernel(
    const unsigned short* __restrict__ aggb, const unsigned short* __restrict__ hinb,
    const unsigned short* __restrict__ WtF, const float* __restrict__ bias,
    unsigned short* __restrict__ hout) {
    __shared__ unsigned short c_s[32][CPITCH];

    int m0 = blockIdx.x * 32;
    int lane = threadIdx.x;
    int half = lane & 15;
    int quad = lane >> 4;
    int kq = quad * 8;

    floatx4 acc[2][8];
    #pragma unroll
    for (int mt = 0; mt < 2; mt++)
        #pragma unroll
        for (int j = 0; j < 8; j++)
            acc[mt][j] = (floatx4){0.f, 0.f, 0.f, 0.f};

    int r0 = min(m0 + half, N_NODES - 1);
    int r1 = min(m0 + 16 + half, N_NODES - 1);

    const short8* Bf = (const short8*)WtF;
    #pragma unroll
    for (int kt = 0; kt < 8; kt++) {
        const unsigned short* abase = (kt < 4) ? aggb : hinb;
        int ka = (kt & 3) * 32 + kq;
        short8 a0 = *((const short8*)(abase + (size_t)r0 * D + ka));
        short8 a1 = *((const short8*)(abase + (size_t)r1 * D + ka));
        #pragma unroll
        for (int j = 0; j < 8; j++) {
            short8 b = Bf[(j * 8 + kt) * 64 + lane];
            acc[0][j] = __builtin_amdgcn_mfma_f32_16x16x32_bf16(a0, b, acc[0][j], 0, 0, 0);
            acc[1][j] = __builtin_amdgcn_mfma_f32_16x16x32_bf16(a1, b, acc[1][j], 0, 0, 0);
        }
    }

    // epilogue: bias+relu -> LDS (bf16) -> coalesced global
    #pragma unroll
    for (int j = 0; j < 8; j++) {
        int col = j * 16 + half;
        float bv = bias[col];
        #pragma unroll
        for (int mt = 0; mt < 2; mt++)
            #pragma unroll
            for (int r = 0; r < 4; r++)
                c_s[mt * 16 + quad * 4 + r][col] = f2bf(fmaxf(acc[mt][j][r] + bv, 0.f));
    }
    __syncthreads();
    #pragma unroll
    for (int t = 0; t < 8; t++) {
        int flat = t * 64 + lane;        // uint4 index in 32x(128/8) tile
        int rl = flat >> 4;
        int c = flat & 15;
        int row = m0 + rl;
        if (row < N_NODES)
            *((uint4*)(hout + (size_t)row * D + c * 8)) = *((const uint4*)&c_s[rl][c * 8]);
    }
}

// ---------------- last layer: GEMM + fused readout ----------------

__global__ __launch_bounds__(64) void gemm_mfma_out_kernel(
    const unsigned short* __restrict__ aggb, const unsigned short* __restrict__ hinb,
    const unsigned short* __restrict__ WtF, const float* __restrict__ bias,
    const float* __restrict__ Wout, const float* __restrict__ bout,
    float* __restrict__ out) {
    int m0 = blockIdx.x * 32;
    int lane = threadIdx.x;
    int half = lane & 15;
    int quad = lane >> 4;
    int kq = quad * 8;

    floatx4 acc[2][8];
    #pragma unroll
    for (int mt = 0; mt < 2; mt++)
        #pragma unroll
        for (int j = 0; j < 8; j++)
            acc[mt][j] = (floatx4){0.f, 0.f, 0.f, 0.f};

    int r0 = min(m0 + half, N_NODES - 1);
    int r1 = min(m0 + 16 + half, N_NODES - 1);

    const short8* Bf = (const short8*)WtF;
    #pragma unroll
    for (int kt = 0; kt < 8; kt++) {
        const unsigned short* abase = (kt < 4) ? aggb : hinb;
        int ka = (kt & 3) * 32 + kq;
        short8 a0 = *((const short8*)(abase + (size_t)r0 * D + ka));
        short8 a1 = *((const short8*)(abase + (size_t)r1 * D + ka));
        #pragma unroll
        for (int j = 0; j < 8; j++) {
            short8 b = Bf[(j * 8 + kt) * 64 + lane];
            acc[0][j] = __builtin_amdgcn_mfma_f32_16x16x32_bf16(a0, b, acc[0][j], 0, 0, 0);
            acc[1][j] = __builtin_amdgcn_mfma_f32_16x16x32_bf16(a1, b, acc[1][j], 0, 0, 0);
        }
    }

    float vout[2][4] = {{0.f, 0.f, 0.f, 0.f}, {0.f, 0.f, 0.f, 0.f}};
    #pragma unroll
    for (int j = 0; j < 8; j++) {
        int col = j * 16 + half;
        float bv = bias[col];
        float wv = Wout[col];
        #pragma unroll
        for (int mt = 0; mt < 2; mt++)
            #pragma unroll
            for (int r = 0; r < 4; r++)
                vout[mt][r] += fmaxf(acc[mt][j][r] + bv, 0.f) * wv;
    }
    #pragma unroll
    for (int off = 1; off < 16; off <<= 1) {
        #pragma unroll
        for (int mt = 0; mt < 2; mt++)
            #pragma unroll
            for (int r = 0; r < 4; r++)
                vout[mt][r] += __shfl_xor(vout[mt][r], off, 64);
    }
    if (half == 0) {
        float bo = bout[0];
        #pragma unroll
        for (int mt = 0; mt < 2; mt++) {
            #pragma unroll
            for (int r = 0; r < 4; r++) {
                int row = m0 + mt * 16 + quad * 4 + r;
                if (row < N_NODES) out[row] = vout[mt][r] + bo;
            }
        }
    }
}

// ---------------- launch ----------------

extern "C" void kernel_launch(void* const* d_in, const int* in_sizes, int n_in,
                              void* d_out, int out_size, void* d_ws, size_t ws_size,
                              hipStream_t stream) {
    const float* x     = (const float*)d_in[0];
    const int*   edge  = (const int*)d_in[1];   // [2, E]: src then dst
    const float* W_l   = (const float*)d_in[2];
    const float* b_l   = (const float*)d_in[3];
    const float* W_r   = (const float*)d_in[4];
    const float* W_out = (const float*)d_in[5];
    const float* b_out = (const float*)d_in[6];
    float* out = (float*)d_out;

    char* ws = (char*)d_ws;
    size_t off = 0;
    auto alloc = [&](size_t bytes) -> void* {
        void* p = ws + off;
        off += (bytes + 255) & ~(size_t)255;
        return p;
    };
    unsigned short* xb   = (unsigned short*)alloc((size_t)N_NODES * D * 2);
    unsigned short* hb   = (unsigned short*)alloc((size_t)N_NODES * D * 2);
    unsigned short* aggb = (unsigned short*)alloc((size_t)N_NODES * D * 2);
    unsigned short* WtF  = (unsigned short*)alloc((size_t)NLAYERS * D * 256 * 2);
    int*   deg       = (int*)alloc((size_t)N_NODES * sizeof(int));
    int*   row_start = (int*)alloc((size_t)N_NODES * sizeof(int));
    int*   cursor    = (int*)alloc((size_t)N_NODES * sizeof(int));
    float* inv_deg   = (float*)alloc((size_t)N_NODES * sizeof(float));
    int*   csr_src   = (int*)alloc((size_t)N_EDGES * sizeof(int));
    int*   counter   = (int*)alloc(256);

    const int* src = edge;
    const int* dst = edge + N_EDGES;

    cvt_init_kernel<<<(CVT_TOTAL + 255) / 256, 256, 0, stream>>>(
        x, W_l, W_r, xb, WtF, deg, cursor, counter);
    hist_kernel<<<(N_EDGES + 255) / 256, 256, 0, stream>>>(dst, deg);
    alloc_kernel<<<(N_NODES + 255) / 256, 256, 0, stream>>>(deg, counter, row_start, inv_deg);
    fill_kernel<<<(N_EDGES + 255) / 256, 256, 0, stream>>>(src, dst, row_start, cursor, csr_src);

    const int agg_grid  = (N_NODES + 15) / 16;
    const int gemm_grid = (N_NODES + 31) / 32;

    // layer 0: xb -> hb
    agg_kernel<<<agg_grid, 256, 0, stream>>>(xb, row_start, deg, csr_src, inv_deg, aggb);
    gemm_mfma_kernel<<<gemm_grid, 64, 0, stream>>>(aggb, xb, WtF, b_l, hb);
    // layer 1: hb -> hb (row-exclusive, safe in-place)
    agg_kernel<<<agg_grid, 256, 0, stream>>>(hb, row_start, deg, csr_src, inv_deg, aggb);
    gemm_mfma_kernel<<<gemm_grid, 64, 0, stream>>>(aggb, hb,
        WtF + (size_t)1 * D * 256, b_l + 1 * D, hb);
    // layer 2: hb -> out (fused readout)
    agg_kernel<<<agg_grid, 256, 0, stream>>>(hb, row_start, deg, csr_src, inv_deg, aggb);
    gemm_mfma_out_kernel<<<gemm_grid, 64, 0, stream>>>(aggb, hb,
        WtF + (size_t)2 * D * 256, b_l + 2 * D, W_out, b_out, out);
}

// Round 7
// 286.025 us; speedup vs baseline: 2.0014x; 1.0282x over previous
//
#include <hip/hip_runtime.h>

#define N_NODES 50000
#define N_EDGES 600000
#define D 128
#define NLAYERS 3
#define CSR_CAP (N_EDGES + 3 * N_NODES)   // padded CSR worst case

typedef __attribute__((ext_vector_type(8))) short short8;
typedef __attribute__((ext_vector_type(4))) float floatx4;

__device__ __forceinline__ float bf_lo(unsigned u) { return __uint_as_float(u << 16); }
__device__ __forceinline__ float bf_hi(unsigned u) { return __uint_as_float(u & 0xffff0000u); }
__device__ __forceinline__ unsigned short f2bf(float f) {
    unsigned u = __float_as_uint(f);
    return (unsigned short)((u + 0x7fffu + ((u >> 16) & 1u)) >> 16);
}

// ---------------- merged: x->bf16, WtF build, zero-init (incl. sentinel rows) --------
// section A: [0, CVT_A)           one float4 of x -> ushort4 of xb
// section B: [CVT_A, +CVT_B)      one bf16 element of WtF (MFMA B-fragment order)
// section C: [+CVT_B, +N_NODES)   zero deg/cursor; j==0 zeroes counter; j<D zeroes pad rows

#define CVT_A (N_NODES * D / 4)              // 1,600,000
#define CVT_B (NLAYERS * D * 256)            // 98,304
#define CVT_TOTAL (CVT_A + CVT_B + N_NODES)

__global__ void cvt_init_kernel(const float* __restrict__ x, const float* __restrict__ Wl,
                                const float* __restrict__ Wr,
                                unsigned short* __restrict__ xb, unsigned short* __restrict__ hb,
                                unsigned short* __restrict__ WtF,
                                int* __restrict__ deg, int* __restrict__ cursor,
                                int* __restrict__ counter) {
    int i = blockIdx.x * blockDim.x + threadIdx.x;
    if (i < CVT_A) {
        float4 v = ((const float4*)x)[i];
        ushort4 o;
        o.x = f2bf(v.x); o.y = f2bf(v.y); o.z = f2bf(v.z); o.w = f2bf(v.w);
        ((ushort4*)xb)[i] = o;
    } else if (i < CVT_A + CVT_B) {
        int t = i - CVT_A;
        int l = t >> 15;
        int r = t & 32767;
        int f = r >> 3;
        int ii = r & 7;
        int jkt = f >> 6;
        int lane = f & 63;
        int j = jkt >> 3;
        int kt = jkt & 7;
        int half = lane & 15;
        int quad = lane >> 4;
        int n = j * 16 + half;
        int k = kt * 32 + quad * 8 + ii;
        float v = (k < D) ? Wl[(size_t)l * D * D + (size_t)k * D + n]
                          : Wr[(size_t)l * D * D + (size_t)(k - D) * D + n];
        WtF[t] = f2bf(v);
    } else if (i < CVT_TOTAL) {
        int j = i - (CVT_A + CVT_B);
        deg[j] = 0;
        cursor[j] = 0;
        if (j == 0) counter[0] = 0;
        if (j < D) {                         // zero the sentinel row N_NODES
            xb[(size_t)N_NODES * D + j] = 0;
            hb[(size_t)N_NODES * D + j] = 0;
        }
    }
}

// ---------------- CSR build ----------------

__global__ void hist_kernel(const int* __restrict__ dst, int* __restrict__ deg) {
    int e = blockIdx.x * blockDim.x + threadIdx.x;
    if (e < N_EDGES) atomicAdd(&deg[dst[e]], 1);
}

// row_start via per-wave scan of PADDED sizes + one atomicAdd per wave; writes sentinel pads
__global__ void alloc_kernel(const int* __restrict__ deg, int* __restrict__ counter,
                             int* __restrict__ row_start, float* __restrict__ inv_deg,
                             int* __restrict__ csr_src) {
    int i = blockIdx.x * blockDim.x + threadIdx.x;
    int lane = threadIdx.x & 63;
    int d = (i < N_NODES) ? deg[i] : 0;
    int pd = (d + 3) & ~3;
    int v = pd;
    #pragma unroll
    for (int off = 1; off < 64; off <<= 1) {
        int t = __shfl_up(v, off, 64);
        if (lane >= off) v += t;
    }
    int total = __shfl(v, 63, 64);
    int base = 0;
    if (lane == 63) base = atomicAdd(counter, total);
    base = __shfl(base, 63, 64);
    if (i < N_NODES) {
        int rs = base + v - pd;
        row_start[i] = rs;
        inv_deg[i] = 1.0f / fmaxf((float)d, 1.0f);
        for (int k = d; k < pd; k++) csr_src[rs + k] = N_NODES;   // sentinel pads
    }
}

__global__ void fill_kernel(const int* __restrict__ src, const int* __restrict__ dst,
                            const int* __restrict__ row_start, int* __restrict__ cursor,
                            int* __restrict__ csr_src) {
    int e = blockIdx.x * blockDim.x + threadIdx.x;
    if (e < N_EDGES) {
        int d_ = dst[e];
        int pos = atomicAdd(&cursor[d_], 1);
        csr_src[row_start[d_] + pos] = src[e];
    }
}

// ---------------- mean aggregation: lane-preloaded indices + 4 loads in flight ----------
// 16 nodes per 256-thread block; 16 lanes per node, 16B per lane.
// Rows padded to multiple of 4 with sentinel (zero) rows -> exact unroll-4.

__global__ void agg_kernel(const unsigned short* __restrict__ h, const int* __restrict__ row_start,
                           const int* __restrict__ deg, const int* __restrict__ csr_src,
                           const float* __restrict__ inv_deg, unsigned short* __restrict__ agg) {
    int node = blockIdx.x * 16 + (threadIdx.x >> 4);
    int q = threadIdx.x & 15;
    if (node >= N_NODES) return;
    int d = deg[node];
    int pd = (d + 3) & ~3;
    int beg = row_start[node];
    float a[8] = {0.f, 0.f, 0.f, 0.f, 0.f, 0.f, 0.f, 0.f};
    float b[8] = {0.f, 0.f, 0.f, 0.f, 0.f, 0.f, 0.f, 0.f};
    for (int e = beg; e < beg + pd; e += 16) {
        int cnt = min(beg + pd - e, 16);                 // multiple of 4
        int idx = csr_src[e + min(q, cnt - 1)];          // coalesced preload of 16 indices
        for (int j = 0; j < cnt; j += 4) {
            int s0 = __shfl(idx, j + 0, 16);
            int s1 = __shfl(idx, j + 1, 16);
            int s2 = __shfl(idx, j + 2, 16);
            int s3 = __shfl(idx, j + 3, 16);
            uint4 v0 = *((const uint4*)(h + (size_t)s0 * D + q * 8));
            uint4 v1 = *((const uint4*)(h + (size_t)s1 * D + q * 8));
            uint4 v2 = *((const uint4*)(h + (size_t)s2 * D + q * 8));
            uint4 v3 = *((const uint4*)(h + (size_t)s3 * D + q * 8));
            a[0] += bf_lo(v0.x); a[1] += bf_hi(v0.x);
            a[2] += bf_lo(v0.y); a[3] += bf_hi(v0.y);
            a[4] += bf_lo(v0.z); a[5] += bf_hi(v0.z);
            a[6] += bf_lo(v0.w); a[7] += bf_hi(v0.w);
            b[0] += bf_lo(v1.x); b[1] += bf_hi(v1.x);
            b[2] += bf_lo(v1.y); b[3] += bf_hi(v1.y);
            b[4] += bf_lo(v1.z); b[5] += bf_hi(v1.z);
            b[6] += bf_lo(v1.w); b[7] += bf_hi(v1.w);
            a[0] += bf_lo(v2.x); a[1] += bf_hi(v2.x);
            a[2] += bf_lo(v2.y); a[3] += bf_hi(v2.y);
            a[4] += bf_lo(v2.z); a[5] += bf_hi(v2.z);
            a[6] += bf_lo(v2.w); a[7] += bf_hi(v2.w);
            b[0] += bf_lo(v3.x); b[1] += bf_hi(v3.x);
            b[2] += bf_lo(v3.y); b[3] += bf_hi(v3.y);
            b[4] += bf_lo(v3.z); b[5] += bf_hi(v3.z);
            b[6] += bf_lo(v3.w); b[7] += bf_hi(v3.w);
        }
    }
    float w = inv_deg[node];
    uint4 o;
    o.x = (unsigned)f2bf((a[0] + b[0]) * w) | ((unsigned)f2bf((a[1] + b[1]) * w) << 16);
    o.y = (unsigned)f2bf((a[2] + b[2]) * w) | ((unsigned)f2bf((a[3] + b[3]) * w) << 16);
    o.z = (unsigned)f2bf((a[4] + b[4]) * w) | ((unsigned)f2bf((a[5] + b[5]) * w) << 16);
    o.w = (unsigned)f2bf((a[6] + b[6]) * w) | ((unsigned)f2bf((a[7] + b[7]) * w) << 16);
    *((uint4*)(agg + (size_t)node * D + q * 8)) = o;
}

// ---------------- MFMA GEMM: hout = relu([agg|hin](bf16) @ W^T + bias) ----------------
// One wave per block, 32 rows x 128 cols, K=256. B from fragment-layout WtF (coalesced).

#define CPITCH 136

__global__ __launch_bounds__(64) void gemm_mfma_kernel(
    const unsigned short* __restrict__ aggb, const unsigned short* __restrict__ hinb,
    const unsigned short* __restrict__ WtF, const float* __restrict__ bias,
    unsigned short* __restrict__ hout) {
    __shared__ unsigned short c_s[32][CPITCH];

    int m0 = blockIdx.x * 32;
    int lane = threadIdx.x;
    int half = lane & 15;
    int quad = lane >> 4;
    int kq = quad * 8;

    floatx4 acc[2][8];
    #pragma unroll
    for (int mt = 0; mt < 2; mt++)
        #pragma unroll
        for (int j = 0; j < 8; j++)
            acc[mt][j] = (floatx4){0.f, 0.f, 0.f, 0.f};

    int r0 = min(m0 + half, N_NODES - 1);
    int r1 = min(m0 + 16 + half, N_NODES - 1);

    const short8* Bf = (const short8*)WtF;
    #pragma unroll
    for (int kt = 0; kt < 8; kt++) {
        const unsigned short* abase = (kt < 4) ? aggb : hinb;
        int ka = (kt & 3) * 32 + kq;
        short8 a0 = *((const short8*)(abase + (size_t)r0 * D + ka));
        short8 a1 = *((const short8*)(abase + (size_t)r1 * D + ka));
        #pragma unroll
        for (int j = 0; j < 8; j++) {
            short8 b = Bf[(j * 8 + kt) * 64 + lane];
            acc[0][j] = __builtin_amdgcn_mfma_f32_16x16x32_bf16(a0, b, acc[0][j], 0, 0, 0);
            acc[1][j] = __builtin_amdgcn_mfma_f32_16x16x32_bf16(a1, b, acc[1][j], 0, 0, 0);
        }
    }

    #pragma unroll
    for (int j = 0; j < 8; j++) {
        int col = j * 16 + half;
        float bv = bias[col];
        #pragma unroll
        for (int mt = 0; mt < 2; mt++)
            #pragma unroll
            for (int r = 0; r < 4; r++)
                c_s[mt * 16 + quad * 4 + r][col] = f2bf(fmaxf(acc[mt][j][r] + bv, 0.f));
    }
    __syncthreads();
    #pragma unroll
    for (int t = 0; t < 8; t++) {
        int flat = t * 64 + lane;
        int rl = flat >> 4;
        int c = flat & 15;
        int row = m0 + rl;
        if (row < N_NODES)
            *((uint4*)(hout + (size_t)row * D + c * 8)) = *((const uint4*)&c_s[rl][c * 8]);
    }
}

// ---------------- last layer: GEMM + fused readout ----------------

__global__ __launch_bounds__(64) void gemm_mfma_out_kernel(
    const unsigned short* __restrict__ aggb, const unsigned short* __restrict__ hinb,
    const unsigned short* __restrict__ WtF, const float* __restrict__ bias,
    const float* __restrict__ Wout, const float* __restrict__ bout,
    float* __restrict__ out) {
    int m0 = blockIdx.x * 32;
    int lane = threadIdx.x;
    int half = lane & 15;
    int quad = lane >> 4;
    int kq = quad * 8;

    floatx4 acc[2][8];
    #pragma unroll
    for (int mt = 0; mt < 2; mt++)
        #pragma unroll
        for (int j = 0; j < 8; j++)
            acc[mt][j] = (floatx4){0.f, 0.f, 0.f, 0.f};

    int r0 = min(m0 + half, N_NODES - 1);
    int r1 = min(m0 + 16 + half, N_NODES - 1);

    const short8* Bf = (const short8*)WtF;
    #pragma unroll
    for (int kt = 0; kt < 8; kt++) {
        const unsigned short* abase = (kt < 4) ? aggb : hinb;
        int ka = (kt & 3) * 32 + kq;
        short8 a0 = *((const short8*)(abase + (size_t)r0 * D + ka));
        short8 a1 = *((const short8*)(abase + (size_t)r1 * D + ka));
        #pragma unroll
        for (int j = 0; j < 8; j++) {
            short8 b = Bf[(j * 8 + kt) * 64 + lane];
            acc[0][j] = __builtin_amdgcn_mfma_f32_16x16x32_bf16(a0, b, acc[0][j], 0, 0, 0);
            acc[1][j] = __builtin_amdgcn_mfma_f32_16x16x32_bf16(a1, b, acc[1][j], 0, 0, 0);
        }
    }

    float vout[2][4] = {{0.f, 0.f, 0.f, 0.f}, {0.f, 0.f, 0.f, 0.f}};
    #pragma unroll
    for (int j = 0; j < 8; j++) {
        int col = j * 16 + half;
        float bv = bias[col];
        float wv = Wout[col];
        #pragma unroll
        for (int mt = 0; mt < 2; mt++)
            #pragma unroll
            for (int r = 0; r < 4; r++)
                vout[mt][r] += fmaxf(acc[mt][j][r] + bv, 0.f) * wv;
    }
    #pragma unroll
    for (int off = 1; off < 16; off <<= 1) {
        #pragma unroll
        for (int mt = 0; mt < 2; mt++)
            #pragma unroll
            for (int r = 0; r < 4; r++)
                vout[mt][r] += __shfl_xor(vout[mt][r], off, 64);
    }
    if (half == 0) {
        float bo = bout[0];
        #pragma unroll
        for (int mt = 0; mt < 2; mt++) {
            #pragma unroll
            for (int r = 0; r < 4; r++) {
                int row = m0 + mt * 16 + quad * 4 + r;
                if (row < N_NODES) out[row] = vout[mt][r] + bo;
            }
        }
    }
}

// ---------------- launch ----------------

extern "C" void kernel_launch(void* const* d_in, const int* in_sizes, int n_in,
                              void* d_out, int out_size, void* d_ws, size_t ws_size,
                              hipStream_t stream) {
    const float* x     = (const float*)d_in[0];
    const int*   edge  = (const int*)d_in[1];   // [2, E]: src then dst
    const float* W_l   = (const float*)d_in[2];
    const float* b_l   = (const float*)d_in[3];
    const float* W_r   = (const float*)d_in[4];
    const float* W_out = (const float*)d_in[5];
    const float* b_out = (const float*)d_in[6];
    float* out = (float*)d_out;

    char* ws = (char*)d_ws;
    size_t off = 0;
    auto alloc = [&](size_t bytes) -> void* {
        void* p = ws + off;
        off += (bytes + 255) & ~(size_t)255;
        return p;
    };
    unsigned short* xb   = (unsigned short*)alloc((size_t)(N_NODES + 1) * D * 2);
    unsigned short* hb   = (unsigned short*)alloc((size_t)(N_NODES + 1) * D * 2);
    unsigned short* aggb = (unsigned short*)alloc((size_t)N_NODES * D * 2);
    unsigned short* WtF  = (unsigned short*)alloc((size_t)NLAYERS * D * 256 * 2);
    int*   deg       = (int*)alloc((size_t)N_NODES * sizeof(int));
    int*   row_start = (int*)alloc((size_t)N_NODES * sizeof(int));
    int*   cursor    = (int*)alloc((size_t)N_NODES * sizeof(int));
    float* inv_deg   = (float*)alloc((size_t)N_NODES * sizeof(float));
    int*   csr_src   = (int*)alloc((size_t)CSR_CAP * sizeof(int));
    int*   counter   = (int*)alloc(256);

    const int* src = edge;
    const int* dst = edge + N_EDGES;

    cvt_init_kernel<<<(CVT_TOTAL + 255) / 256, 256, 0, stream>>>(
        x, W_l, W_r, xb, hb, WtF, deg, cursor, counter);
    hist_kernel<<<(N_EDGES + 255) / 256, 256, 0, stream>>>(dst, deg);
    alloc_kernel<<<(N_NODES + 255) / 256, 256, 0, stream>>>(deg, counter, row_start, inv_deg, csr_src);
    fill_kernel<<<(N_EDGES + 255) / 256, 256, 0, stream>>>(src, dst, row_start, cursor, csr_src);

    const int agg_grid  = (N_NODES + 15) / 16;
    const int gemm_grid = (N_NODES + 31) / 32;

    // layer 0: xb -> hb
    agg_kernel<<<agg_grid, 256, 0, stream>>>(xb, row_start, deg, csr_src, inv_deg, aggb);
    gemm_mfma_kernel<<<gemm_grid, 64, 0, stream>>>(aggb, xb, WtF, b_l, hb);
    // layer 1: hb -> hb (row-exclusive, safe in-place; sentinel row untouched/zero)
    agg_kernel<<<agg_grid, 256, 0, stream>>>(hb, row_start, deg, csr_src, inv_deg, aggb);
    gemm_mfma_kernel<<<gemm_grid, 64, 0, stream>>>(aggb, hb,
        WtF + (size_t)1 * D * 256, b_l + 1 * D, hb);
    // layer 2: hb -> out (fused readout)
    agg_kernel<<<agg_grid, 256, 0, stream>>>(hb, row_start, deg, csr_src, inv_deg, aggb);
    gemm_mfma_out_kernel<<<gemm_grid, 64, 0, stream>>>(aggb, hb,
        WtF + (size_t)2 * D * 256, b_l + 2 * D, W_out, b_out, out);
}